// Round 5
// baseline (145.342 us; speedup 1.0000x reference)
//
#include <hip/hip_runtime.h>

#define NT 256

// ============================================================================
// 2 lanes per problem. Lane q (=tid&1) owns rows 4q..4q+3 of every 8x8 matrix,
// stored in a conjugated frame M' = P M P (P: col -> col^4) for q=1.
// Conjugation commutes with matmul + elementwise ops, so the Magnus algebra
// is computed unchanged in-frame. Partner rows arrive via __shfl_xor(.,1) and
// are consumed with a compile-time col^4 reindex. All register indices are
// compile-time constants (no scratch demotion).
// ============================================================================

__device__ __forceinline__ float sh1(float x) { return __shfl_xor(x, 1); }

// acc (4x8) += / -=  X (4x8 half) @ Y (full matrix; my 4 rows + partner's 4)
template <int SGN>
__device__ __forceinline__ void mmh(float (&acc)[32], const float (&X)[32],
                                    const float (&Y)[32]) {
#pragma unroll
    for (int kk = 0; kk < 4; ++kk) {
        // local contribution: frame-row kk of Y is resident
#pragma unroll
        for (int r = 0; r < 4; ++r) {
            const float x = SGN > 0 ? X[r * 8 + kk] : -X[r * 8 + kk];
#pragma unroll
            for (int j = 0; j < 8; ++j)
                acc[r * 8 + j] = fmaf(x, Y[kk * 8 + j], acc[r * 8 + j]);
        }
        // remote contribution: partner's stored row kk == my frame row 4+kk,
        // columns xor-4 permuted
        float w[8];
#pragma unroll
        for (int c = 0; c < 8; ++c) w[c] = sh1(Y[kk * 8 + c]);
#pragma unroll
        for (int r = 0; r < 4; ++r) {
            const float x = SGN > 0 ? X[r * 8 + 4 + kk] : -X[r * 8 + 4 + kk];
#pragma unroll
            for (int j = 0; j < 8; ++j)
                acc[r * 8 + j] = fmaf(x, w[j ^ 4], acc[r * 8 + j]);
        }
    }
}

__global__ __launch_bounds__(NT, 4)   // honest design point: <=128 VGPR, 4 waves/EU
void magnus6_kernel(const float* __restrict__ A,
                    const float* __restrict__ hp,
                    const float* __restrict__ y0,
                    float* __restrict__ out,
                    int B)
{
    // alpha3 half-matrix spill: 8 float4 / thread = 128 B -> 32 KB/block.
    // Private column per thread, no barriers.
    __shared__ float4 lds[8][NT];

    const int tx = threadIdx.x;
    const int t  = blockIdx.x * NT + tx;
    const int p  = t >> 1;        // problem index
    const int q  = t & 1;         // which half of the rows
    if (p >= B) return;

    const float h    = hp[0];
    const float c_a2 = h * 1.2909944487358056f;   // h*sqrt(15)/3
    const float c_a3 = h * (10.0f / 3.0f);
    const float c_m  = 20.0f / 3.0f;

    const float* __restrict__ Ab = A + (size_t)p * 192;
    const int rbase = 4 * q;      // my global rows: rbase..rbase+3
    const int c0 = 4 * q;         // my-half columns first (frame layout)
    const int c1 = 4 - c0;

    float R1[32];   // alpha1 -> Omega0 -> Omega      (rows 0..3 of frame)
    float R2[32];   // A1 -> alpha2 -> Q
    float R3[32];   // C1 -> T' -> P'

    // ---- load A1, A2, A3 row-wise; build alpha1, alpha2, alpha3 ----
#pragma unroll
    for (int r = 0; r < 4; ++r) {
        const float* rowA1 = Ab + (rbase + r) * 8;
        const float* rowA2 = rowA1 + 64;
        const float* rowA3 = rowA1 + 128;
        float4 a1lo = *reinterpret_cast<const float4*>(rowA1 + c0);
        float4 a1hi = *reinterpret_cast<const float4*>(rowA1 + c1);
        float4 a2lo = *reinterpret_cast<const float4*>(rowA2 + c0);
        float4 a2hi = *reinterpret_cast<const float4*>(rowA2 + c1);
        float4 a3lo = *reinterpret_cast<const float4*>(rowA3 + c0);
        float4 a3hi = *reinterpret_cast<const float4*>(rowA3 + c1);
        float A1e[8] = {a1lo.x, a1lo.y, a1lo.z, a1lo.w, a1hi.x, a1hi.y, a1hi.z, a1hi.w};
        float A2e[8] = {a2lo.x, a2lo.y, a2lo.z, a2lo.w, a2hi.x, a2hi.y, a2hi.z, a2hi.w};
        float A3e[8] = {a3lo.x, a3lo.y, a3lo.z, a3lo.w, a3hi.x, a3hi.y, a3hi.z, a3hi.w};
        float a3v[8];
#pragma unroll
        for (int j = 0; j < 8; ++j) {
            const float al1 = h * A2e[j];                       // alpha1
            R1[r * 8 + j] = al1;
            a3v[j] = c_a3 * (A1e[j] + A3e[j]) - c_m * al1;       // alpha3
            R2[r * 8 + j] = c_a2 * (A3e[j] - A1e[j]);            // alpha2
        }
        lds[2 * r + 0][tx] = make_float4(a3v[0], a3v[1], a3v[2], a3v[3]);
        lds[2 * r + 1][tx] = make_float4(a3v[4], a3v[5], a3v[6], a3v[7]);
    }

    // ---- C1 = [alpha1, alpha2] into R3 ----
#pragma unroll
    for (int i = 0; i < 32; ++i) R3[i] = 0.0f;
    mmh<+1>(R3, R1, R2);
    mmh<-1>(R3, R2, R1);

    // ---- T' = (C1 + 2*alpha3)/60 (alpha3 from LDS) ----
#pragma unroll
    for (int c = 0; c < 8; ++c) {
        float4 v = lds[c][tx];
        const float vv[4] = {v.x, v.y, v.z, v.w};
#pragma unroll
        for (int j = 0; j < 4; ++j) {
            const int idx = 4 * c + j;
            R3[idx] = fmaf(R3[idx], (1.0f / 60.0f), (1.0f / 30.0f) * vv[j]);
        }
    }

    // ---- Q = alpha2 - alpha1@T' + T'@alpha1 (in place into R2) ----
    mmh<-1>(R2, R1, R3);
    mmh<+1>(R2, R3, R1);

    // ---- P' = T'/4 - alpha1/12 - alpha3/80 (R3); Omega0 = alpha1 + alpha3/12 (R1) ----
#pragma unroll
    for (int c = 0; c < 8; ++c) {
        float4 v = lds[c][tx];
        const float vv[4] = {v.x, v.y, v.z, v.w};
#pragma unroll
        for (int j = 0; j < 4; ++j) {
            const int idx = 4 * c + j;
            const float a3e = vv[j];
            const float a1e = R1[idx];
            R3[idx] = 0.25f * R3[idx] - (1.0f / 12.0f) * a1e - (1.0f / 80.0f) * a3e;
            R1[idx] = a1e + (1.0f / 12.0f) * a3e;
        }
    }

    // ---- Omega = Omega0 + P'@Q - Q@P' (into R1) ----
    mmh<+1>(R1, R3, R2);
    mmh<-1>(R1, R2, R3);

    // ---- y = expm(Omega) @ y0, Taylor order 6; vectors split 4+4 (no col perm) ----
    float4 y0v = *reinterpret_cast<const float4*>(y0 + (size_t)p * 8 + rbase);
    float v[4] = {y0v.x, y0v.y, y0v.z, y0v.w};
    float y[4] = {v[0], v[1], v[2], v[3]};

    const float inv[6] = {1.0f, 0.5f, 1.0f / 3.0f, 0.25f, 0.2f, 1.0f / 6.0f};
#pragma unroll
    for (int k = 0; k < 6; ++k) {
        float vr[4];
#pragma unroll
        for (int kk = 0; kk < 4; ++kk) vr[kk] = sh1(v[kk]);   // my frame v'[4+kk]
        float w[4];
#pragma unroll
        for (int r = 0; r < 4; ++r) {
            float s = 0.0f;
#pragma unroll
            for (int j = 0; j < 4; ++j) s = fmaf(R1[r * 8 + j], v[j], s);
#pragma unroll
            for (int j = 0; j < 4; ++j) s = fmaf(R1[r * 8 + 4 + j], vr[j], s);
            w[r] = s * inv[k];
        }
#pragma unroll
        for (int r = 0; r < 4; ++r) { v[r] = w[r]; y[r] += v[r]; }
    }

    *reinterpret_cast<float4*>(out + (size_t)p * 8 + rbase) =
        make_float4(y[0], y[1], y[2], y[3]);
}

extern "C" void kernel_launch(void* const* d_in, const int* in_sizes, int n_in,
                              void* d_out, int out_size, void* d_ws, size_t ws_size,
                              hipStream_t stream)
{
    const float* A  = (const float*)d_in[0];
    const float* hp = (const float*)d_in[1];
    const float* y0 = (const float*)d_in[2];
    float* out = (float*)d_out;

    const int B = in_sizes[2] / 8;        // y0 is (B, 8)
    const int nthreads = 2 * B;           // 2 lanes per problem
    const int grid = (nthreads + NT - 1) / NT;
    magnus6_kernel<<<grid, NT, 0, stream>>>(A, hp, y0, out, B);
}

// Round 6
// 26.319 us; speedup vs baseline: 5.5223x; 5.5223x over previous
//
#include <hip/hip_runtime.h>

#define NT 256

// ============================================================================
// 4 lanes per problem. Quad-lane q (=tid&3) owns global rows {2q, 2q+1} of
// every 8x8 matrix (16 floats per matrix). No frame permutation: row k=2o+s
// of any matrix is fetched from quad slot o with a single DPP quad_perm
// broadcast (VALU pipe, compile-time pattern, no DS/bpermute, no lgkmcnt).
// Live set ~60 floats -> fits even a 64-VGPR allocation: spill-proof under
// the allocator's aggressive-occupancy heuristic (R2-R5 post-mortems).
// ============================================================================

__device__ __forceinline__ void st4(float* dst, float4 v) {
    dst[0] = v.x; dst[1] = v.y; dst[2] = v.z; dst[3] = v.w;
}

// Broadcast x from quad slot O to all 4 lanes of the quad (quad_perm[O,O,O,O]).
template <int O>
__device__ __forceinline__ float qb(float x) {
    return __int_as_float(__builtin_amdgcn_mov_dpp(
        __float_as_int(x), O * 0x55, 0xF, 0xF, true));
}

// acc(2x8) += SGN * X(2x8) @ Y, contribution from Y's rows {2O, 2O+1}
// (held by quad slot O).
template <int SGN, int O>
__device__ __forceinline__ void mm4_o(float (&acc)[16], const float (&X)[16],
                                      const float (&Y)[16]) {
#pragma unroll
    for (int s = 0; s < 2; ++s) {           // global k = 2O + s
        float w[8];
#pragma unroll
        for (int j = 0; j < 8; ++j) w[j] = qb<O>(Y[s * 8 + j]);
#pragma unroll
        for (int r = 0; r < 2; ++r) {
            const float x = SGN > 0 ? X[r * 8 + 2 * O + s]
                                    : -X[r * 8 + 2 * O + s];
#pragma unroll
            for (int j = 0; j < 8; ++j)
                acc[r * 8 + j] = fmaf(x, w[j], acc[r * 8 + j]);
        }
    }
}

template <int SGN>
__device__ __forceinline__ void mm4(float (&acc)[16], const float (&X)[16],
                                    const float (&Y)[16]) {
    mm4_o<SGN, 0>(acc, X, Y);
    mm4_o<SGN, 1>(acc, X, Y);
    mm4_o<SGN, 2>(acc, X, Y);
    mm4_o<SGN, 3>(acc, X, Y);
}

// One Taylor mat-vec contribution from Omega columns {2O, 2O+1}.
template <int O>
__device__ __forceinline__ void tay_o(float (&w)[2], const float (&Om)[16],
                                      const float (&v)[2]) {
    const float vk0 = qb<O>(v[0]);
    const float vk1 = qb<O>(v[1]);
#pragma unroll
    for (int r = 0; r < 2; ++r) {
        w[r] = fmaf(Om[r * 8 + 2 * O], vk0, w[r]);
        w[r] = fmaf(Om[r * 8 + 2 * O + 1], vk1, w[r]);
    }
}

__global__ __launch_bounds__(NT)
void magnus6_kernel(const float* __restrict__ A,
                    const float* __restrict__ hp,
                    const float* __restrict__ y0,
                    float* __restrict__ out,
                    int B)
{
    // alpha3 spill: 4 float4 / thread = 64 B -> 16 KB/block. Private column,
    // no barriers; 8 blocks/CU x 16 KB = 128 KB <= 160 KB (not binding).
    __shared__ float4 lds[4][NT];

    const int tx = threadIdx.x;
    const int t  = blockIdx.x * NT + tx;
    const int p  = t >> 2;          // problem index
    const int q  = t & 3;           // quad slot: owns rows 2q, 2q+1
    if (p >= B) return;

    const float h    = hp[0];
    const float c_a2 = h * 1.2909944487358056f;   // h*sqrt(15)/3
    const float c_a3 = h * (10.0f / 3.0f);
    const float c_m  = 20.0f / 3.0f;

    // A is (B,3,8,8). My rows of A1 start at float offset p*192 + q*16;
    // A2/A3 at +64/+128 floats (= +16/+32 float4s).
    const float4* __restrict__ Ap =
        reinterpret_cast<const float4*>(A + (size_t)p * 192 + q * 16);

    float R1[16];   // alpha1 -> Omega0 -> Omega
    float R2[16];   // alpha2 -> Q (commutator accumulated in place)
    float R3[16];   // C1 -> T' -> P'

    // ---- stream-load A1,A2,A3; build alpha1(R1), alpha2(R2), alpha3(LDS) ----
#pragma unroll
    for (int c = 0; c < 4; ++c) {
        float4 v1 = Ap[c], v2 = Ap[16 + c], v3 = Ap[32 + c];
        float A1e[4], A2e[4], A3e[4], a3v[4];
        st4(A1e, v1); st4(A2e, v2); st4(A3e, v3);
#pragma unroll
        for (int j = 0; j < 4; ++j) {
            const float al1 = h * A2e[j];                       // alpha1
            R1[4 * c + j] = al1;
            R2[4 * c + j] = c_a2 * (A3e[j] - A1e[j]);           // alpha2
            a3v[j] = c_a3 * (A1e[j] + A3e[j]) - c_m * al1;      // alpha3
        }
        lds[c][tx] = make_float4(a3v[0], a3v[1], a3v[2], a3v[3]);
    }

    // ---- C1 = [alpha1, alpha2] into R3 ----
#pragma unroll
    for (int i = 0; i < 16; ++i) R3[i] = 0.0f;
    mm4<+1>(R3, R1, R2);
    mm4<-1>(R3, R2, R1);

    // ---- T' = (C1 + 2*alpha3)/60 ----
#pragma unroll
    for (int c = 0; c < 4; ++c) {
        float4 v = lds[c][tx];
        float vv[4]; st4(vv, v);
#pragma unroll
        for (int j = 0; j < 4; ++j) {
            const int idx = 4 * c + j;
            R3[idx] = fmaf(R3[idx], (1.0f / 60.0f), (1.0f / 30.0f) * vv[j]);
        }
    }

    // ---- Q = alpha2 - alpha1@T' + T'@alpha1  (in place into R2) ----
    mm4<-1>(R2, R1, R3);
    mm4<+1>(R2, R3, R1);

    // ---- P' = T'/4 - alpha1/12 - alpha3/80 (R3); Omega0 = alpha1 + alpha3/12 (R1) ----
#pragma unroll
    for (int c = 0; c < 4; ++c) {
        float4 v = lds[c][tx];
        float vv[4]; st4(vv, v);
#pragma unroll
        for (int j = 0; j < 4; ++j) {
            const int idx = 4 * c + j;
            const float a3e = vv[j];
            const float a1e = R1[idx];
            R3[idx] = 0.25f * R3[idx] - (1.0f / 12.0f) * a1e - (1.0f / 80.0f) * a3e;
            R1[idx] = a1e + (1.0f / 12.0f) * a3e;
        }
    }

    // ---- Omega = Omega0 + P'@Q - Q@P'  (into R1) ----
    mm4<+1>(R1, R3, R2);
    mm4<-1>(R1, R2, R3);

    // ---- y = expm(Omega) @ y0, Taylor order 6; lane holds y rows 2q,2q+1 ----
    const float2 y0v = *reinterpret_cast<const float2*>(y0 + (size_t)p * 8 + 2 * q);
    float v[2] = {y0v.x, y0v.y};
    float y[2] = {v[0], v[1]};

    const float inv[6] = {1.0f, 0.5f, 1.0f / 3.0f, 0.25f, 0.2f, 1.0f / 6.0f};
#pragma unroll
    for (int k = 0; k < 6; ++k) {
        float w[2] = {0.0f, 0.0f};
        tay_o<0>(w, R1, v);
        tay_o<1>(w, R1, v);
        tay_o<2>(w, R1, v);
        tay_o<3>(w, R1, v);
#pragma unroll
        for (int r = 0; r < 2; ++r) { v[r] = w[r] * inv[k]; y[r] += v[r]; }
    }

    *reinterpret_cast<float2*>(out + (size_t)p * 8 + 2 * q) = make_float2(y[0], y[1]);
}

extern "C" void kernel_launch(void* const* d_in, const int* in_sizes, int n_in,
                              void* d_out, int out_size, void* d_ws, size_t ws_size,
                              hipStream_t stream)
{
    const float* A  = (const float*)d_in[0];
    const float* hp = (const float*)d_in[1];
    const float* y0 = (const float*)d_in[2];
    float* out = (float*)d_out;

    const int B = in_sizes[2] / 8;        // y0 is (B, 8)
    const int nthreads = 4 * B;           // 4 lanes per problem
    const int grid = (nthreads + NT - 1) / NT;
    magnus6_kernel<<<grid, NT, 0, stream>>>(A, hp, y0, out, B);
}

// Round 7
// 24.532 us; speedup vs baseline: 5.9245x; 1.0728x over previous
//
#include <hip/hip_runtime.h>

#define NT 256

// ============================================================================
// 4 lanes per problem (quad slot q = tid&3 owns global rows {2q, 2q+1} of all
// 8x8 matrices). Cross-lane row fetch = DPP quad_perm broadcast (VALU pipe).
// NEW vs R6: matrices stored as column-PAIRS (v2f) and all matmul/elementwise
// FMAs emitted as packed v_pk_fma_f32 via __builtin_elementwise_fma -> ~2x
// fewer FMA instructions. Layout: M[r*4+jj] = (row r, cols 2jj, 2jj+1),
// r in {0,1} local (global rows 2q+r). All register indices compile-time.
// Live set ~56-64 VGPR: spill-proof under the allocator's 8-wave/EU budget.
// ============================================================================

typedef float v2f __attribute__((ext_vector_type(2)));

// Broadcast x from quad slot O to all 4 lanes of the quad (quad_perm[O,O,O,O]).
template <int O>
__device__ __forceinline__ float qb(float x) {
    return __int_as_float(__builtin_amdgcn_mov_dpp(
        __float_as_int(x), O * 0x55, 0xF, 0xF, true));
}
template <int O>
__device__ __forceinline__ v2f qb2(v2f y) {
    v2f r;
    r.x = qb<O>(y.x);
    r.y = qb<O>(y.y);
    return r;
}
__device__ __forceinline__ v2f pkfma(v2f a, v2f b, v2f c) {
    return __builtin_elementwise_fma(a, b, c);   // -> v_pk_fma_f32
}

// acc(2x8, col-pairs) += SGN * X(2x8) @ Y, contribution from Y's global rows
// {2O, 2O+1} (held by quad slot O as its local rows 0,1).
template <int SGN, int O>
__device__ __forceinline__ void mm4_o(v2f (&acc)[8], const v2f (&X)[8],
                                      const v2f (&Y)[8]) {
#pragma unroll
    for (int s = 0; s < 2; ++s) {            // global k = 2O + s
        v2f w2[4];
#pragma unroll
        for (int jj = 0; jj < 4; ++jj) w2[jj] = qb2<O>(Y[s * 4 + jj]);
#pragma unroll
        for (int r = 0; r < 2; ++r) {
            // X(row r, col k=2O+s) lives in pair X[r*4+O], component s.
            const float x0 = (s == 0) ? X[r * 4 + O].x : X[r * 4 + O].y;
            const float xs = (SGN > 0) ? x0 : -x0;
            const v2f xx = {xs, xs};
#pragma unroll
            for (int jj = 0; jj < 4; ++jj)
                acc[r * 4 + jj] = pkfma(xx, w2[jj], acc[r * 4 + jj]);
        }
    }
}

template <int SGN>
__device__ __forceinline__ void mm4(v2f (&acc)[8], const v2f (&X)[8],
                                    const v2f (&Y)[8]) {
    mm4_o<SGN, 0>(acc, X, Y);
    mm4_o<SGN, 1>(acc, X, Y);
    mm4_o<SGN, 2>(acc, X, Y);
    mm4_o<SGN, 3>(acc, X, Y);
}

__global__ __launch_bounds__(NT)
void magnus6_kernel(const float* __restrict__ A,
                    const float* __restrict__ hp,
                    const float* __restrict__ y0,
                    float* __restrict__ out,
                    int B)
{
    // alpha3 spill: 4 float4 / thread = 64 B -> 16 KB/block, private column,
    // no barriers; not occupancy-binding.
    __shared__ float4 lds[4][NT];

    const int tx = threadIdx.x;
    const int t  = blockIdx.x * NT + tx;
    const int p  = t >> 2;          // problem index
    const int q  = t & 3;           // quad slot: owns rows 2q, 2q+1
    if (p >= B) return;

    const float h    = hp[0];
    const float c_a2 = h * 1.2909944487358056f;   // h*sqrt(15)/3
    const float c_a3 = h * (10.0f / 3.0f);
    const float c_m  = 20.0f / 3.0f;

    // A is (B,3,8,8). My rows of A1 start at float offset p*192 + q*16.
    const float4* __restrict__ Ap =
        reinterpret_cast<const float4*>(A + (size_t)p * 192 + q * 16);

    v2f R1[8];   // alpha1 -> Omega0 -> Omega
    v2f R2[8];   // alpha2 -> Q (commutator accumulated in place)
    v2f R3[8];   // C1 -> T' -> P'

    // ---- stream-load A1,A2,A3; build alpha1(R1), alpha2(R2), alpha3(LDS) ----
    // chunk c: local row c>>1, cols (c&1)*4 .. +3  -> pairs b, b+1
#pragma unroll
    for (int c = 0; c < 4; ++c) {
        float4 v1 = Ap[c], v2 = Ap[16 + c], v3 = Ap[32 + c];
        const int b = (c >> 1) * 4 + (c & 1) * 2;
        v2f A1lo = {v1.x, v1.y}, A1hi = {v1.z, v1.w};
        v2f A2lo = {v2.x, v2.y}, A2hi = {v2.z, v2.w};
        v2f A3lo = {v3.x, v3.y}, A3hi = {v3.z, v3.w};
        v2f al1lo = h * A2lo, al1hi = h * A2hi;            // alpha1
        R1[b] = al1lo; R1[b + 1] = al1hi;
        R2[b]     = c_a2 * (A3lo - A1lo);                  // alpha2
        R2[b + 1] = c_a2 * (A3hi - A1hi);
        v2f a3lo = c_a3 * (A1lo + A3lo) - c_m * al1lo;     // alpha3
        v2f a3hi = c_a3 * (A1hi + A3hi) - c_m * al1hi;
        lds[c][tx] = make_float4(a3lo.x, a3lo.y, a3hi.x, a3hi.y);
    }

    // ---- C1 = [alpha1, alpha2] into R3 ----
#pragma unroll
    for (int i = 0; i < 8; ++i) R3[i] = (v2f){0.0f, 0.0f};
    mm4<+1>(R3, R1, R2);
    mm4<-1>(R3, R2, R1);

    // ---- T' = (C1 + 2*alpha3)/60 ----
#pragma unroll
    for (int c = 0; c < 4; ++c) {
        float4 v = lds[c][tx];
        v2f a3lo = {v.x, v.y}, a3hi = {v.z, v.w};
        const int b = (c >> 1) * 4 + (c & 1) * 2;
        const v2f k60 = {1.0f / 60.0f, 1.0f / 60.0f};
        R3[b]     = pkfma(R3[b],     k60, (1.0f / 30.0f) * a3lo);
        R3[b + 1] = pkfma(R3[b + 1], k60, (1.0f / 30.0f) * a3hi);
    }

    // ---- Q = alpha2 - alpha1@T' + T'@alpha1  (in place into R2) ----
    mm4<-1>(R2, R1, R3);
    mm4<+1>(R2, R3, R1);

    // ---- P' = T'/4 - alpha1/12 - alpha3/80 (R3); Omega0 = alpha1 + alpha3/12 (R1) ----
#pragma unroll
    for (int c = 0; c < 4; ++c) {
        float4 v = lds[c][tx];
        v2f a3lo = {v.x, v.y}, a3hi = {v.z, v.w};
        const int b = (c >> 1) * 4 + (c & 1) * 2;
        v2f t0 = R3[b], t1 = R3[b + 1];
        v2f a10 = R1[b], a11 = R1[b + 1];
        R3[b]     = 0.25f * t0 - (1.0f / 12.0f) * a10 - (1.0f / 80.0f) * a3lo;
        R3[b + 1] = 0.25f * t1 - (1.0f / 12.0f) * a11 - (1.0f / 80.0f) * a3hi;
        R1[b]     = a10 + (1.0f / 12.0f) * a3lo;
        R1[b + 1] = a11 + (1.0f / 12.0f) * a3hi;
    }

    // ---- Omega = Omega0 + P'@Q - Q@P'  (into R1) ----
    mm4<+1>(R1, R3, R2);
    mm4<-1>(R1, R2, R3);

    // ---- y = expm(Omega) @ y0, Taylor order 6; lane holds y rows 2q,2q+1 ----
    const float2 y0v = *reinterpret_cast<const float2*>(y0 + (size_t)p * 8 + 2 * q);
    float v0 = y0v.x, v1 = y0v.y;
    float yy0 = v0, yy1 = v1;

    const float inv[6] = {1.0f, 0.5f, 1.0f / 3.0f, 0.25f, 0.2f, 1.0f / 6.0f};
#pragma unroll
    for (int k = 0; k < 6; ++k) {
        v2f acc0 = {0.0f, 0.0f}, acc1 = {0.0f, 0.0f};
        // vw2[jj] = (v_global[2jj], v_global[2jj+1]) via quad broadcasts
        {
            v2f vw;
            vw.x = qb<0>(v0); vw.y = qb<0>(v1);
            acc0 = pkfma(R1[0], vw, acc0); acc1 = pkfma(R1[4], vw, acc1);
            vw.x = qb<1>(v0); vw.y = qb<1>(v1);
            acc0 = pkfma(R1[1], vw, acc0); acc1 = pkfma(R1[5], vw, acc1);
            vw.x = qb<2>(v0); vw.y = qb<2>(v1);
            acc0 = pkfma(R1[2], vw, acc0); acc1 = pkfma(R1[6], vw, acc1);
            vw.x = qb<3>(v0); vw.y = qb<3>(v1);
            acc0 = pkfma(R1[3], vw, acc0); acc1 = pkfma(R1[7], vw, acc1);
        }
        v0 = (acc0.x + acc0.y) * inv[k];
        v1 = (acc1.x + acc1.y) * inv[k];
        yy0 += v0;
        yy1 += v1;
    }

    *reinterpret_cast<float2*>(out + (size_t)p * 8 + 2 * q) = make_float2(yy0, yy1);
}

extern "C" void kernel_launch(void* const* d_in, const int* in_sizes, int n_in,
                              void* d_out, int out_size, void* d_ws, size_t ws_size,
                              hipStream_t stream)
{
    const float* A  = (const float*)d_in[0];
    const float* hp = (const float*)d_in[1];
    const float* y0 = (const float*)d_in[2];
    float* out = (float*)d_out;

    const int B = in_sizes[2] / 8;        // y0 is (B, 8)
    const int nthreads = 4 * B;           // 4 lanes per problem
    const int grid = (nthreads + NT - 1) / NT;
    magnus6_kernel<<<grid, NT, 0, stream>>>(A, hp, y0, out, B);
}